// Round 14
// baseline (480.716 us; speedup 1.0000x reference)
//
#include <hip/hip_runtime.h>
#include <math.h>

#define NBUS 30000
#define NGEN 6000
#define NEL 250000
#define NEG 12000

#define AS1 __attribute__((address_space(1)))
#define AS3 __attribute__((address_space(3)))

typedef unsigned short u16;
typedef __attribute__((ext_vector_type(8))) short bf16x8;
typedef __attribute__((ext_vector_type(4))) float f32x4;

__device__ __forceinline__ u16 f2b(float x) {  // fp32 -> bf16 RNE
  unsigned u = __float_as_uint(x);
  unsigned r = (u + 0x7FFFu + ((u >> 16) & 1u)) >> 16;
  return (u16)r;
}
__device__ __forceinline__ float b2f(u16 x) {
  return __uint_as_float((unsigned)x << 16);
}
__device__ __forceinline__ f32x4 splat4(float v) {
  f32x4 r = {v, v, v, v};
  return r;
}
__device__ __forceinline__ f32x4 b2f4(ushort4 v) {
  f32x4 r;
  r.x = b2f(v.x); r.y = b2f(v.y); r.z = b2f(v.z); r.w = b2f(v.w);
  return r;
}

// 16-lane sum reduce via DPP (VALU pipe, no LDS latency):
// quad_perm xor1, xor2 -> quad sums; row_ror:4 + row_ror:8 -> row sum.
#define DPP_ADD(v, ctrl) \
  v += __uint_as_float((unsigned)__builtin_amdgcn_update_dpp( \
      0, (int)__float_as_uint(v), (ctrl), 0xF, 0xF, true))
#define RED16(v) do { \
    DPP_ADD(v, 0xB1);  /* quad_perm(1,0,3,2): xor1 */ \
    DPP_ADD(v, 0x4E);  /* quad_perm(2,3,0,1): xor2 */ \
    DPP_ADD(v, 0x124); /* row_ror:4 */ \
    DPP_ADD(v, 0x128); /* row_ror:8 */ \
  } while (0)

__global__ void zeroi(int* __restrict__ p, int n) {
  int i = blockIdx.x * blockDim.x + threadIdx.x;
  int st = gridDim.x * blockDim.x;
  for (; i < n; i += st) p[i] = 0;
}

// ---------------- batched CSR build over 3 edge types ----------------
struct CsrArgs {
  const int* dst[3];
  const int* src[3];
  const float* ea[3];
  const float* tmp0;  // temp scalars per layer (each: 3 edge types)
  const float* tmp1;
  const float* tmp2;
  int* cnt[3];      // histogram; later reused as scatter cursor
  int* rowptr[3];
  int* srcC[3];
  float* eaC[3];
  int* psum[3];
  int E[3];
  int N[3];
};

__global__ void hist_b(CsrArgs a) {
  int ty = blockIdx.y;
  int i = blockIdx.x * 256 + threadIdx.x;
  if (i < a.E[ty]) atomicAdd(&a.cnt[ty][a.dst[ty][i]], 1);
}

__global__ __launch_bounds__(1024) void scan_p1(CsrArgs a) {
  int ty = blockIdx.y;
  int n = a.N[ty];
  int base = blockIdx.x * 1024;
  if (base >= n) return;
  int tid = threadIdx.x, lane = tid & 63, wv = tid >> 6;
  int i = base + tid;
  int v = (i < n) ? a.cnt[ty][i] : 0;
#pragma unroll
  for (int off = 32; off >= 1; off >>= 1) v += __shfl_xor(v, off);
  __shared__ int w[16];
  if (lane == 0) w[wv] = v;
  __syncthreads();
  if (tid < 16) {
    int t = w[tid];
#pragma unroll
    for (int off = 8; off >= 1; off >>= 1) t += __shfl_xor(t, off, 16);
    if (tid == 0) a.psum[ty][blockIdx.x] = t;
  }
}

__global__ __launch_bounds__(64) void scan_p2(CsrArgs a) {
  int ty = blockIdx.y;
  int nb = (a.N[ty] + 1023) / 1024;
  int tid = threadIdx.x;
  int v = (tid < nb) ? a.psum[ty][tid] : 0;
  int x = v;
#pragma unroll
  for (int off = 1; off < 64; off <<= 1) {
    int y = __shfl_up(x, off, 64);
    if (tid >= off) x += y;
  }
  if (tid < nb) a.psum[ty][tid] = x - v;  // exclusive
}

__global__ __launch_bounds__(1024) void scan_p3(CsrArgs a) {
  int ty = blockIdx.y;
  int n = a.N[ty];
  int base = blockIdx.x * 1024;
  if (base >= n) return;
  int tid = threadIdx.x, lane = tid & 63, wv = tid >> 6;
  int i = base + tid;
  int v = (i < n) ? a.cnt[ty][i] : 0;
  int x = v;
#pragma unroll
  for (int off = 1; off < 64; off <<= 1) {
    int y = __shfl_up(x, off, 64);
    if (lane >= off) x += y;
  }
  __shared__ int w[16];
  if (lane == 63) w[wv] = x;
  __syncthreads();
  if (tid < 16) {
    int t = w[tid];
#pragma unroll
    for (int off = 1; off < 16; off <<= 1) {
      int y = __shfl_up(t, off, 16);
      if (tid >= off) t += y;
    }
    w[tid] = t;
  }
  __syncthreads();
  int woff = (wv == 0) ? 0 : w[wv - 1];
  int incl = a.psum[ty][blockIdx.x] + woff + x;
  if (i < n) {
    a.rowptr[ty][i + 1] = incl;
    a.cnt[ty][i] = incl - v;  // cursor (exclusive)
  }
  if (i == 0) a.rowptr[ty][0] = 0;
}

// Fused scatter+gather: one pass over edges; reads dst/src/ea coalesced,
// writes srcC + eaC record at the cursor slot directly (no eidx indirection).
// eaC record: [e0,e1,e2,e3,e4, t0*inv, t1*inv, t2*inv] (temp pre-folded).
__global__ void scatter_b(CsrArgs a) {
  int ty = blockIdx.y;
  int i = blockIdx.x * 256 + threadIdx.x;
  if (i >= a.E[ty]) return;
  int p = atomicAdd(&a.cnt[ty][a.dst[ty][i]], 1);
  a.srcC[ty][p] = a.src[ty][i];
  const float* s = a.ea[ty] + (size_t)i * 6;
  float e3 = s[3];
  float inv = 1.f / fmaxf(e3, 1e-6f);
  float4 r0 = make_float4(s[0], s[1], s[2], e3);
  float4 r1 = make_float4(s[4], a.tmp0[ty] * inv, a.tmp1[ty] * inv,
                          a.tmp2[ty] * inv);
  float* d = a.eaC[ty] + (size_t)p * 8;
  *(float4*)d = r0;
  *(float4*)(d + 4) = r1;
}

// ---------------- merged projections: bus cast + gen 16->32 proj ----------
__global__ void proj_cast(const float* __restrict__ xb, const float* __restrict__ xg,
                          const float* __restrict__ w, const float* __restrict__ b,
                          u16* __restrict__ ob, u16* __restrict__ og, int nCast) {
  if ((int)blockIdx.x < nCast) {
    int i = blockIdx.x * 256 + threadIdx.x;
    if (i < NBUS * 32) ob[i] = f2b(xb[i]);
  } else {
    int idx = (blockIdx.x - nCast) * 256 + threadIdx.x;
    if (idx >= NGEN * 32) return;
    int i = idx >> 5, c = idx & 31;
    float acc = b[c];
#pragma unroll
    for (int k = 0; k < 16; ++k) acc += xg[i * 16 + k] * w[k * 32 + c];
    og[idx] = f2b(acc);
  }
}

struct PackArgs {
  const float* src[24];
  int off[24];
  int lgN[24];
  int total[24];
  int K[24];
};
__global__ void pack_multi(PackArgs a, u16* __restrict__ Wt) {
  int j = blockIdx.y;
  int idx = blockIdx.x * 256 + threadIdx.x;
  if (idx >= a.total[j]) return;
  int N1 = (1 << a.lgN[j]) - 1;
  int n = idx & N1;
  int k = idx >> a.lgN[j];
  Wt[(size_t)a.off[j] + (size_t)n * a.K[j] + k] = f2b(a.src[j][idx]);
}

// Merged bus+gen GEMM: global_load_lds w=16, XOR swizzle.
// Epilogue: C restaged through LDS -> 16B/lane coalesced bf16x8 stores.
__global__ __launch_bounds__(256) void gemm_both(
    const u16* __restrict__ Ab, const u16* __restrict__ Ag,
    const u16* __restrict__ Wt, int goff,
    u16* __restrict__ Cb, u16* __restrict__ Cg,
    int K, int Nb, int Ng, int ybus)
{
  __shared__ __align__(16) u16 As[128 * 32];
  __shared__ __align__(16) u16 Bs[128 * 32];
  __shared__ __align__(16) u16 Cs[32 * 128];
  const int t = threadIdx.x;
  const int w = t >> 6, lane = t & 63;
  const u16* A; const u16* W; u16* C; int M, Ncols, bn;
  if ((int)blockIdx.y < ybus) {
    A = Ab; W = Wt; C = Cb; M = NBUS; Ncols = Nb; bn = blockIdx.y * 128;
  } else {
    A = Ag; W = Wt + goff; C = Cg; M = NGEN; Ncols = Ng; bn = (blockIdx.y - ybus) * 128;
  }
  const int bm = blockIdx.x * 128;
  if (bm >= M) return;
  const int wm = (w & 1) * 64, wn = (w >> 1) * 64;
  const int lr = lane & 15, q = lane >> 4;
  const int srow = lane >> 2;
  const int blk = (lane & 3) ^ (srow & 3);
  f32x4 acc[4][4] = {};
  for (int k0 = 0; k0 < K; k0 += 32) {
#pragma unroll
    for (int sseg = 0; sseg < 2; ++sseg) {
      int seg = w + (sseg << 2);
      int row = (seg << 4) + srow;
      int ga = bm + row; if (ga > M - 1) ga = M - 1;
      const u16* gpa = A + (size_t)ga * K + k0 + (blk << 3);
      __builtin_amdgcn_global_load_lds((AS1 void*)gpa, (AS3 void*)(As + (seg << 9)),
                                       16, 0, 0);
      int gb = bn + row;
      const u16* gpb = W + (size_t)gb * K + k0 + (blk << 3);
      __builtin_amdgcn_global_load_lds((AS1 void*)gpb, (AS3 void*)(Bs + (seg << 9)),
                                       16, 0, 0);
    }
    __syncthreads();
    bf16x8 af[4], bg[4];
#pragma unroll
    for (int i = 0; i < 4; ++i) {
      int r = wm + i * 16 + lr;
      af[i] = *(const bf16x8*)&As[(r << 5) + ((q ^ (r & 3)) << 3)];
    }
#pragma unroll
    for (int j = 0; j < 4; ++j) {
      int r = wn + j * 16 + lr;
      bg[j] = *(const bf16x8*)&Bs[(r << 5) + ((q ^ (r & 3)) << 3)];
    }
#pragma unroll
    for (int i = 0; i < 4; ++i)
#pragma unroll
      for (int j = 0; j < 4; ++j)
        acc[i][j] = __builtin_amdgcn_mfma_f32_16x16x32_bf16(
            af[i], bg[j], acc[i][j], 0, 0, 0);
    __syncthreads();
  }
  // coalesced C-write: per i-block, stage 32x128 u16 in LDS, then 16B/lane
#pragma unroll
  for (int i = 0; i < 4; ++i) {
    __syncthreads();
    int lrow = (wm >> 2) + q * 4;   // wm=0 -> rows 0-15, wm=64 -> rows 16-31
#pragma unroll
    for (int j = 0; j < 4; ++j)
#pragma unroll
      for (int r = 0; r < 4; ++r)
        Cs[(lrow + r) * 128 + wn + j * 16 + lr] = f2b(acc[i][j][r]);
    __syncthreads();
#pragma unroll
    for (int it = 0; it < 2; ++it) {
      int chunk = t + it * 256;        // 512 chunks of 8 u16 (16B)
      int row = chunk >> 4;            // 0..31
      int cg = (chunk & 15) * 8;       // 0..120
      int grow = bm + ((row & 16) ? 64 : 0) + i * 16 + (row & 15);
      int gcol = bn + cg;
      if (grow < M && gcol < Ncols)
        *(bf16x8*)&C[(size_t)grow * Ncols + gcol] =
            *(const bf16x8*)&Cs[row * 128 + cg];
    }
  }
}

// ---------------- fused GATv2 conv ----------------
// R13 body exactly (depth-2 pair pipeline, DPP reduces everywhere, SGPR ea
// loads, 32-bit gather math, 44 VGPR). Block geometry 256->512 threads
// (8 waves = 8 nodes/block, 4500 blocks): tests the CP dispatch-rate floor
// (~160 blocks/us across R4/R9/R13) at finer placement granularity than
// R10's 16-wave blocks (which fragmented: max 2 placements/CU).

#define CS_F1(lv, ev, fv, idx) do { \
    int rc_ = (idx) < nch ? (idx) : nch - 1; \
    int s_ = __builtin_amdgcn_readlane(vsrc, rc_); \
    lv = *(const ushort4*)(xl + (size_t)(unsigned)(s_ * ldl + ch)); \
    const float* ep_ = ebase + (unsigned)(rc_ * 8); \
    ev = *(const float4*)ep_; \
    fv = *(const float4*)(ep_ + 4); \
  } while (0)

#define CS_FETCH(S, base) do { \
    CS_F1(l##S##0, e##S##0, f##S##0, (base)); \
    CS_F1(l##S##1, e##S##1, f##S##1, (base) + 1); \
  } while (0)

#define CS_EDGE(xv, ev, fv, pv) do { \
    f32x4 m_ = xv + rx; \
    m_ = __builtin_elementwise_fma(splat4(ev.x), w0, m_); \
    m_ = __builtin_elementwise_fma(splat4(ev.y), w1, m_); \
    m_ = __builtin_elementwise_fma(splat4(ev.z), w2, m_); \
    m_ = __builtin_elementwise_fma(splat4(ev.w), w3, m_); \
    m_ = __builtin_elementwise_fma(splat4(fv.x), w4, m_); \
    float t_ = (TS == 1) ? fv.y : (TS == 2) ? fv.z : fv.w; \
    m_ = __builtin_elementwise_fma(splat4(t_), w5, m_); \
    m_ = __builtin_elementwise_max(m_, m_ * 0.2f); \
    pv = m_.x * av.x; \
    pv = fmaf(m_.y, av.y, pv); \
    pv = fmaf(m_.z, av.z, pv); \
    pv = fmaf(m_.w, av.w, pv); \
  } while (0)

#define CS_COMPUTE(S, base) do { \
    f32x4 x0_ = b2f4(l##S##0), x1_ = b2f4(l##S##1); \
    float p0_, p1_; \
    CS_EDGE(x0_, e##S##0, f##S##0, p0_); \
    CS_EDGE(x1_, e##S##1, f##S##1, p1_); \
    RED16(p0_); \
    RED16(p1_); \
    if ((base) >= nch) p0_ = -INFINITY; \
    if ((base) + 1 >= nch) p1_ = -INFINITY; \
    float nm_ = fmaxf(mx, fmaxf(p0_, p1_)); \
    float sc_ = __expf(mx - nm_); \
    float q0_ = __expf(p0_ - nm_), q1_ = __expf(p1_ - nm_); \
    mx = nm_; \
    den = den * sc_ + (q0_ + q1_); \
    acc = acc * splat4(sc_); \
    acc = __builtin_elementwise_fma(splat4(q0_), x0_, acc); \
    acc = __builtin_elementwise_fma(splat4(q1_), x1_, acc); \
  } while (0)

template<int TS>
__device__ __forceinline__ f32x4 conv_set(
    int node, int beg, int end, int ch,
    const int* __restrict__ srcc, const float* __restrict__ eac,
    const u16* __restrict__ xl, int ldl,
    const u16* __restrict__ xr, int ldr,
    const float* __restrict__ We, const float* __restrict__ att)
{
  f32x4 w0 = *(const f32x4*)(We + ch);
  f32x4 w1 = *(const f32x4*)(We + 256 + ch);
  f32x4 w2 = *(const f32x4*)(We + 512 + ch);
  f32x4 w3 = *(const f32x4*)(We + 768 + ch);
  f32x4 w4 = *(const f32x4*)(We + 1024 + ch);
  f32x4 w5 = *(const f32x4*)(We + 1280 + ch);
  f32x4 av = *(const f32x4*)(att + ch);
  f32x4 rx = b2f4(*(const ushort4*)(xr + (size_t)(unsigned)(node * ldr + ch)));
  float mx = -INFINITY, den = 0.f;
  f32x4 acc = {0.f, 0.f, 0.f, 0.f};
  int lane = ch >> 2;

  for (int cb = beg; cb < end; cb += 64) {
    int nch = end - cb;
    if (nch > 64) nch = 64;
    nch = __builtin_amdgcn_readfirstlane(nch);           // prove uniform
    int cbu = __builtin_amdgcn_readfirstlane(cb);        // prove uniform
    const float* ebase = eac + (size_t)(unsigned)cbu * 8u;
    int li = lane < nch ? lane : nch - 1;
    int vsrc = srcc[cb + li];   // one coalesced load covers 64 source indices
    int np = (nch + 1) >> 1;

    ushort4 la0, la1, lb0, lb1;
    float4 ea0, ea1, eb0, eb1;
    float4 fa0, fa1, fb0, fb1;

    CS_FETCH(a, 0);
    int g = 0;
    for (; g + 2 < np; g += 2) {
      CS_FETCH(b, (g + 1) << 1);
      CS_COMPUTE(a, g << 1);
      CS_FETCH(a, (g + 2) << 1);
      CS_COMPUTE(b, (g + 1) << 1);
    }
    if (g + 1 < np) {
      CS_FETCH(b, (g + 1) << 1);
      CS_COMPUTE(a, g << 1);
      CS_COMPUTE(b, (g + 1) << 1);
    } else {
      CS_COMPUTE(a, g << 1);
    }
  }
  float inv = 1.f / (den + 1e-16f);
  return acc * splat4(inv);
}

struct ConvP {
  const int* __restrict__ rpA; const int* __restrict__ srcA;
  const float* __restrict__ eaA;
  const u16* __restrict__ xlA; const u16* __restrict__ xrA;
  const float* __restrict__ WeA; const float* __restrict__ attA;
  const int* __restrict__ rpB; const int* __restrict__ srcB;
  const float* __restrict__ eaB;
  const u16* __restrict__ xlB; const u16* __restrict__ xrB;
  const float* __restrict__ WeB; const float* __restrict__ attB;
  const float* __restrict__ b1; const float* __restrict__ b2;
  const float* __restrict__ lnw; const float* __restrict__ lnb;
  const u16* __restrict__ res16;
  float* __restrict__ outf; u16* __restrict__ out16;
  int ldlA, ldrA, ldlB, ldrB, ld16, N;
};

// One launch per layer: blocks [0,nbBus) do bus nodes, [nbBus,..) gen nodes.
// 512 threads = 8 waves = 8 nodes per block.
// MODE 0: LN256 + bf16-residual + ELU, write bf16 state.
// MODE 1: head-mean + LN64 + bf16-residual, write d_out (fp32).
template<int MODE, int TS>
__global__ __launch_bounds__(512) void conv_fused(ConvP bus, ConvP gen, int nbBus) {
  const bool isb = (int)blockIdx.x < nbBus;
  const int grp = isb ? blockIdx.x : blockIdx.x - nbBus;
#define SEL(f) (isb ? bus.f : gen.f)
  const int* __restrict__ rpA = SEL(rpA);
  const int* __restrict__ srcA = SEL(srcA);
  const float* __restrict__ eaA = SEL(eaA);
  const u16* __restrict__ xlA = SEL(xlA);
  const u16* __restrict__ xrA = SEL(xrA);
  const float* __restrict__ WeA = SEL(WeA);
  const float* __restrict__ attA = SEL(attA);
  const int* __restrict__ rpB = SEL(rpB);
  const int N = SEL(N);
  const int ldlA = SEL(ldlA), ldrA = SEL(ldrA);

  int node = grp * 8 + (threadIdx.x >> 6);
  int lane = threadIdx.x & 63;
  if (node >= N) return;
  int ch = lane << 2;
  int begA = rpA[node], endA = rpA[node + 1];
  int begB = 0, endB = 0;
  if (rpB) { begB = rpB[node]; endB = rpB[node + 1]; }  // overlap rp chains
  f32x4 o = conv_set<TS>(node, begA, endA, ch, srcA, eaA, xlA, ldlA,
                         xrA, ldrA, WeA, attA);
  if (rpB && begB < endB) {  // uniform branch; gen side has rpB==null
    f32x4 ob = conv_set<TS>(node, begB, endB, ch, SEL(srcB), SEL(eaB),
                            SEL(xlB), SEL(ldlB), SEL(xrB), SEL(ldrB),
                            SEL(WeB), SEL(attB));
    o[0] += ob[0]; o[1] += ob[1]; o[2] += ob[2]; o[3] += ob[3];
  }
  const float* __restrict__ b1 = SEL(b1);
  const float* __restrict__ b2 = SEL(b2);
  const float* __restrict__ lnw = SEL(lnw);
  const float* __restrict__ lnb = SEL(lnb);
  const u16* __restrict__ res16 = SEL(res16);
  const int ld16 = SEL(ld16);
  if (MODE == 0) {
    int c = ch;
    float4 bb = *(const float4*)(b1 + c);
    float v0 = o[0] + bb.x, v1 = o[1] + bb.y, v2 = o[2] + bb.z, v3 = o[3] + bb.w;
    if (b2) {
      float4 b2v = *(const float4*)(b2 + c);
      v0 += b2v.x; v1 += b2v.y; v2 += b2v.z; v3 += b2v.w;
    }
    // LN256 reduces: DPP within 16 lanes, shfl for xor16/xor32 only
    float s = v0 + v1 + v2 + v3;
    RED16(s);
    s += __shfl_xor(s, 16); s += __shfl_xor(s, 32);
    float mu = s * (1.f / 256.f);
    float d0 = v0 - mu, d1 = v1 - mu, d2 = v2 - mu, d3 = v3 - mu;
    float q = d0*d0 + d1*d1 + d2*d2 + d3*d3;
    RED16(q);
    q += __shfl_xor(q, 16); q += __shfl_xor(q, 32);
    float rs = rsqrtf(q * (1.f / 256.f) + 1e-5f);
    float4 lw = *(const float4*)(lnw + c);
    float4 lb = *(const float4*)(lnb + c);
    float y0 = d0 * rs * lw.x + lb.x;
    float y1 = d1 * rs * lw.y + lb.y;
    float y2 = d2 * rs * lw.z + lb.z;
    float y3 = d3 * rs * lw.w + lb.w;
    ushort4 r = *(const ushort4*)(res16 + (size_t)node * ld16 + c);
    y0 += b2f(r.x); y1 += b2f(r.y); y2 += b2f(r.z); y3 += b2f(r.w);
    // ELU via HW v_exp (expm1f is a slow libm polynomial); tol 0.0625 >> err
    y0 = (y0 > 0.f) ? y0 : __expf(y0) - 1.f;
    y1 = (y1 > 0.f) ? y1 : __expf(y1) - 1.f;
    y2 = (y2 > 0.f) ? y2 : __expf(y2) - 1.f;
    y3 = (y3 > 0.f) ? y3 : __expf(y3) - 1.f;
    ushort4 o16;
    o16.x = f2b(y0); o16.y = f2b(y1); o16.z = f2b(y2); o16.w = f2b(y3);
    u16* __restrict__ out16 = SEL(out16);
    *(ushort4*)(out16 + (size_t)node * 256 + c) = o16;
  } else {
    // head mean: sum over the 4 head groups (lanes xor 16, 32)
    float h0 = o[0], h1 = o[1], h2 = o[2], h3 = o[3];
    h0 += __shfl_xor(h0, 16); h0 += __shfl_xor(h0, 32);
    h1 += __shfl_xor(h1, 16); h1 += __shfl_xor(h1, 32);
    h2 += __shfl_xor(h2, 16); h2 += __shfl_xor(h2, 32);
    h3 += __shfl_xor(h3, 16); h3 += __shfl_xor(h3, 32);
    int cc = (lane & 15) << 2;
    float4 bb = *(const float4*)(b1 + cc);
    float v0 = 0.25f * h0 + bb.x, v1 = 0.25f * h1 + bb.y;
    float v2 = 0.25f * h2 + bb.z, v3 = 0.25f * h3 + bb.w;
    if (b2) {
      float4 b2v = *(const float4*)(b2 + cc);
      v0 += b2v.x; v1 += b2v.y; v2 += b2v.z; v3 += b2v.w;
    }
    // LN64 reduces are exact 16-lane sums -> pure DPP
    float s = v0 + v1 + v2 + v3;
    RED16(s);
    float mu = s * (1.f / 64.f);
    float d0 = v0 - mu, d1 = v1 - mu, d2 = v2 - mu, d3 = v3 - mu;
    float q = d0*d0 + d1*d1 + d2*d2 + d3*d3;
    RED16(q);
    float rs = rsqrtf(q * (1.f / 64.f) + 1e-5f);
    float4 lw = *(const float4*)(lnw + cc);
    float4 lb = *(const float4*)(lnb + cc);
    ushort4 r = *(const ushort4*)(res16 + (size_t)node * ld16 + cc);
    float y0 = d0 * rs * lw.x + lb.x + b2f(r.x);
    float y1 = d1 * rs * lw.y + lb.y + b2f(r.y);
    float y2 = d2 * rs * lw.z + lb.z + b2f(r.z);
    float y3 = d3 * rs * lw.w + lb.w + b2f(r.w);
    float* __restrict__ outf = SEL(outf);
    if (lane < 16)
      *(float4*)(outf + (size_t)node * 64 + cc) = make_float4(y0, y1, y2, y3);
  }
#undef SEL
}

extern "C" void kernel_launch(void* const* d_in, const int* in_sizes, int n_in,
                              void* d_out, int out_size, void* d_ws, size_t ws_size,
                              hipStream_t stream) {
  const float* x_bus = (const float*)d_in[0];
  const float* x_gen = (const float*)d_in[1];
  const float* ea[3] = {(const float*)d_in[2], (const float*)d_in[3], (const float*)d_in[4]};
  const float* pw = (const float*)d_in[5];
  const float* pb = (const float*)d_in[6];
  const float* Wl[3] = {(const float*)d_in[7], (const float*)d_in[15], (const float*)d_in[23]};
  const float* Wr[3] = {(const float*)d_in[8], (const float*)d_in[16], (const float*)d_in[24]};
  const float* We[3] = {(const float*)d_in[9], (const float*)d_in[17], (const float*)d_in[25]};
  const float* att[3] = {(const float*)d_in[10], (const float*)d_in[18], (const float*)d_in[26]};
  const float* bc[3] = {(const float*)d_in[11], (const float*)d_in[19], (const float*)d_in[27]};
  const float* temp[3] = {(const float*)d_in[12], (const float*)d_in[20], (const float*)d_in[28]};
  const float* lnw[3] = {(const float*)d_in[13], (const float*)d_in[21], (const float*)d_in[29]};
  const float* lnb[3] = {(const float*)d_in[14], (const float*)d_in[22], (const float*)d_in[30]};
  const float* rp0_w = (const float*)d_in[31];
  const float* rp2_w = (const float*)d_in[33];
  const int* srcs[3] = {(const int*)d_in[35], (const int*)d_in[37], (const int*)d_in[39]};
  const int* dsts[3] = {(const int*)d_in[36], (const int*)d_in[38], (const int*)d_in[40]};

  float* ws = (float*)d_ws;
  size_t off = 0;
  auto alloc = [&](size_t n) { float* p = ws + off; off += n; return p; };
  u16* xb16_0 = (u16*)alloc((size_t)NBUS * 16);
  u16* xg16_0 = (u16*)alloc((size_t)NGEN * 16);
  u16* xb16 = (u16*)alloc((size_t)NBUS * 128);
  u16* xg16 = (u16*)alloc((size_t)NGEN * 128);
  u16* Pbus = (u16*)alloc((size_t)NBUS * 640);
  u16* Pgen = (u16*)alloc((size_t)NGEN * 384);
  u16* Wt = (u16*)alloc((size_t)886000 / 2);  // 884736 packed elements + pad
  float* eaC0 = alloc((size_t)NEL * 8);
  float* eaC1 = alloc((size_t)NEG * 8);
  float* eaC2 = alloc((size_t)NEG * 8);
  int* cw_all = (int*)alloc(NBUS + NBUS + NGEN);  // 3 histograms, contiguous
  int* rp_line = (int*)alloc(NBUS + 1);
  int* rp_g2b = (int*)alloc(NBUS + 1);
  int* rp_b2g = (int*)alloc(NGEN + 1);
  int* sc_line = (int*)alloc(NEL);
  int* sc_g2b = (int*)alloc(NEG);
  int* sc_b2g = (int*)alloc(NEG);
  int* psum = (int*)alloc(3 * 32);
  (void)ws_size; (void)in_sizes; (void)n_in; (void)out_size;

  CsrArgs ca;
  for (int t = 0; t < 3; ++t) { ca.dst[t] = dsts[t]; ca.src[t] = srcs[t]; ca.ea[t] = ea[t]; }
  ca.tmp0 = temp[0]; ca.tmp1 = temp[1]; ca.tmp2 = temp[2];
  ca.cnt[0] = cw_all; ca.cnt[1] = cw_all + NBUS; ca.cnt[2] = cw_all + 2 * NBUS;
  ca.rowptr[0] = rp_line; ca.rowptr[1] = rp_g2b; ca.rowptr[2] = rp_b2g;
  ca.srcC[0] = sc_line; ca.srcC[1] = sc_g2b; ca.srcC[2] = sc_b2g;
  ca.eaC[0] = eaC0; ca.eaC[1] = eaC1; ca.eaC[2] = eaC2;
  ca.psum[0] = psum; ca.psum[1] = psum + 32; ca.psum[2] = psum + 64;
  ca.E[0] = NEL; ca.E[1] = NEG; ca.E[2] = NEG;
  ca.N[0] = NBUS; ca.N[1] = NBUS; ca.N[2] = NGEN;

  int egrid = (NEL + 255) / 256;
  hipLaunchKernelGGL(zeroi, dim3(64), dim3(1024), 0, stream, cw_all, 2 * NBUS + NGEN);
  hipLaunchKernelGGL(hist_b, dim3(egrid, 3), dim3(256), 0, stream, ca);
  hipLaunchKernelGGL(scan_p1, dim3(30, 3), dim3(1024), 0, stream, ca);
  hipLaunchKernelGGL(scan_p2, dim3(1, 3), dim3(64), 0, stream, ca);
  hipLaunchKernelGGL(scan_p3, dim3(30, 3), dim3(1024), 0, stream, ca);
  hipLaunchKernelGGL(scatter_b, dim3(egrid, 3), dim3(256), 0, stream, ca);

  // merged bus-cast + gen-proj
  const int nCast = (NBUS * 32 + 255) / 256;              // 3750
  const int nProj = (NGEN * 32 + 255) / 256;              // 750
  hipLaunchKernelGGL(proj_cast, dim3(nCast + nProj), dim3(256), 0, stream,
                     x_bus, x_gen, pw, pb, xb16_0, xg16_0, nCast);

  // ---- single upfront pack of all 3 layers (+ residual projections) ----
  const int K_l[3] = {32, 256, 256};
  const int Nbus_l[3] = {1280, 1024, 1088};
  const int Ngen_l[3] = {768, 512, 576};
  int Lbase[3], goff_l[3];
  {
    int b = 0;
    for (int l = 0; l < 3; ++l) {
      Lbase[l] = b;
      goff_l[l] = Nbus_l[l] * K_l[l];
      b += (Nbus_l[l] + Ngen_l[l]) * K_l[l];
    }
  }
  PackArgs pa = {};
  int ns = 0;
  auto add = [&](const float* src, int offel, int N_, int lg, int K) {
    pa.src[ns] = src; pa.off[ns] = offel; pa.lgN[ns] = lg;
    pa.total[ns] = K * N_; pa.K[ns] = K; ++ns;
  };
  for (int l = 0; l < 3; ++l) {
    int K = K_l[l];
    size_t sl = (size_t)K * 256;
    int L = Lbase[l], go = goff_l[l];
    add(Wl[l], L, 256, 8, K);
    add(Wr[l], L + 256 * K, 256, 8, K);
    add(Wr[l] + sl, L + 512 * K, 256, 8, K);
    add(Wl[l] + 2 * sl, L + 768 * K, 256, 8, K);
    add(Wl[l] + sl, L + go, 256, 8, K);
    add(Wr[l] + 2 * sl, L + go + 256 * K, 256, 8, K);
    if (l == 0) {
      add(rp0_w, L + 1024 * K, 256, 8, K);
      add(rp0_w + 32 * 256, L + go + 512 * K, 256, 8, K);
    } else if (l == 2) {
      add(rp2_w, L + 1024 * K, 64, 6, K);
      add(rp2_w + 256 * 64, L + go + 512 * K, 64, 6, K);
    }
  }
  hipLaunchKernelGGL(pack_multi, dim3(256, ns), dim3(256), 0, stream, pa, Wt);

  const int nbBus = (NBUS + 7) / 8;   // 3750
  const int nbGen = (NGEN + 7) / 8;   // 750

  for (int l = 0; l < 3; ++l) {
    const int K = K_l[l];
    const int Nb = Nbus_l[l], Ng = Ngen_l[l];
    const u16* Ab = (l == 0) ? xb16_0 : xb16;
    const u16* Ag = (l == 0) ? xg16_0 : xg16;

    // --- merged bus+gen projection GEMM ---
    int ybus = (Nb + 127) / 128, ygen = (Ng + 127) / 128;
    hipLaunchKernelGGL(gemm_both, dim3((NBUS + 127) / 128, ybus + ygen),
                       dim3(256), 0, stream,
                       Ab, Ag, Wt + Lbase[l], goff_l[l], Pbus, Pgen, K, Nb, Ng, ybus);

    // --- fused conv + LN/residual/activation (one launch: bus + gen) ---
    ConvP pb_ = {};
    pb_.rpA = rp_line; pb_.srcA = sc_line; pb_.eaA = eaC0;
    pb_.xlA = Pbus; pb_.ldlA = Nb; pb_.xrA = Pbus + 256; pb_.ldrA = Nb;
    pb_.WeA = We[l]; pb_.attA = att[l];
    pb_.rpB = rp_g2b; pb_.srcB = sc_g2b; pb_.eaB = eaC1;
    pb_.xlB = Pgen; pb_.ldlB = Ng; pb_.xrB = Pbus + 512; pb_.ldrB = Nb;
    pb_.WeB = We[l] + 1536; pb_.attB = att[l] + 256;
    pb_.N = NBUS;
    ConvP pg_ = {};
    pg_.rpA = rp_b2g; pg_.srcA = sc_b2g; pg_.eaA = eaC2;
    pg_.xlA = Pbus + 768; pg_.ldlA = Nb; pg_.xrA = Pgen + 256; pg_.ldrA = Ng;
    pg_.WeA = We[l] + 3072; pg_.attA = att[l] + 512;
    pg_.rpB = nullptr;
    pg_.N = NGEN;
    dim3 gall(nbBus + nbGen), blk(512);

    if (l < 2) {
      pb_.b1 = bc[l]; pb_.b2 = bc[l] + 256; pb_.lnw = lnw[l]; pb_.lnb = lnb[l];
      pg_.b1 = bc[l] + 512; pg_.b2 = nullptr;
      pg_.lnw = lnw[l] + 256; pg_.lnb = lnb[l] + 256;
      if (l == 0) {
        pb_.res16 = Pbus + 1024; pb_.ld16 = Nb;
        pg_.res16 = Pgen + 512; pg_.ld16 = Ng;
      } else {
        pb_.res16 = xb16; pb_.ld16 = 256;   // read-before-write per node: safe
        pg_.res16 = xg16; pg_.ld16 = 256;
      }
      pb_.outf = nullptr; pb_.out16 = xb16;
      pg_.outf = nullptr; pg_.out16 = xg16;
      if (l == 0)
        hipLaunchKernelGGL((conv_fused<0, 1>), gall, blk, 0, stream, pb_, pg_, nbBus);
      else
        hipLaunchKernelGGL((conv_fused<0, 2>), gall, blk, 0, stream, pb_, pg_, nbBus);
    } else {
      pb_.b1 = bc[2]; pb_.b2 = bc[2] + 64; pb_.lnw = lnw[2]; pb_.lnb = lnb[2];
      pb_.res16 = Pbus + 1024; pb_.ld16 = Nb;
      pb_.outf = (float*)d_out; pb_.out16 = nullptr;
      pg_.b1 = bc[2] + 128; pg_.b2 = nullptr; pg_.lnw = lnw[2] + 64; pg_.lnb = lnb[2] + 64;
      pg_.res16 = Pgen + 512; pg_.ld16 = Ng;
      pg_.outf = (float*)d_out + (size_t)NBUS * 64; pg_.out16 = nullptr;
      hipLaunchKernelGGL((conv_fused<1, 3>), gall, blk, 0, stream, pb_, pg_, nbBus);
    }
  }
}

// Round 15
// 438.212 us; speedup vs baseline: 1.0970x; 1.0970x over previous
//
#include <hip/hip_runtime.h>
#include <math.h>

#define NBUS 30000
#define NGEN 6000
#define NEL 250000
#define NEG 12000

#define AS1 __attribute__((address_space(1)))
#define AS3 __attribute__((address_space(3)))

typedef unsigned short u16;
typedef __attribute__((ext_vector_type(8))) short bf16x8;
typedef __attribute__((ext_vector_type(4))) float f32x4;

__device__ __forceinline__ u16 f2b(float x) {  // fp32 -> bf16 RNE
  unsigned u = __float_as_uint(x);
  unsigned r = (u + 0x7FFFu + ((u >> 16) & 1u)) >> 16;
  return (u16)r;
}
__device__ __forceinline__ float b2f(u16 x) {
  return __uint_as_float((unsigned)x << 16);
}
__device__ __forceinline__ f32x4 splat4(float v) {
  f32x4 r = {v, v, v, v};
  return r;
}
__device__ __forceinline__ f32x4 b2f4(ushort4 v) {
  f32x4 r;
  r.x = b2f(v.x); r.y = b2f(v.y); r.z = b2f(v.z); r.w = b2f(v.w);
  return r;
}

// 16-lane sum reduce via DPP (VALU pipe, no LDS latency):
// quad_perm xor1, xor2 -> quad sums; row_ror:4 + row_ror:8 -> row sum.
#define DPP_ADD(v, ctrl) \
  v += __uint_as_float((unsigned)__builtin_amdgcn_update_dpp( \
      0, (int)__float_as_uint(v), (ctrl), 0xF, 0xF, true))
#define RED16(v) do { \
    DPP_ADD(v, 0xB1);  /* quad_perm(1,0,3,2): xor1 */ \
    DPP_ADD(v, 0x4E);  /* quad_perm(2,3,0,1): xor2 */ \
    DPP_ADD(v, 0x124); /* row_ror:4 */ \
    DPP_ADD(v, 0x128); /* row_ror:8 */ \
  } while (0)

__global__ void zeroi(int* __restrict__ p, int n) {
  int i = blockIdx.x * blockDim.x + threadIdx.x;
  int st = gridDim.x * blockDim.x;
  for (; i < n; i += st) p[i] = 0;
}

// ---------------- batched CSR build over 3 edge types ----------------
struct CsrArgs {
  const int* dst[3];
  const int* src[3];
  const float* ea[3];
  const float* tmp0;  // temp scalars per layer (each: 3 edge types)
  const float* tmp1;
  const float* tmp2;
  int* cnt[3];      // histogram; later reused as scatter cursor
  int* rowptr[3];
  int* srcC[3];
  float* eaC[3];
  int* psum[3];
  int E[3];
  int N[3];
};

__global__ void hist_b(CsrArgs a) {
  int ty = blockIdx.y;
  int i = blockIdx.x * 256 + threadIdx.x;
  if (i < a.E[ty]) atomicAdd(&a.cnt[ty][a.dst[ty][i]], 1);
}

__global__ __launch_bounds__(1024) void scan_p1(CsrArgs a) {
  int ty = blockIdx.y;
  int n = a.N[ty];
  int base = blockIdx.x * 1024;
  if (base >= n) return;
  int tid = threadIdx.x, lane = tid & 63, wv = tid >> 6;
  int i = base + tid;
  int v = (i < n) ? a.cnt[ty][i] : 0;
#pragma unroll
  for (int off = 32; off >= 1; off >>= 1) v += __shfl_xor(v, off);
  __shared__ int w[16];
  if (lane == 0) w[wv] = v;
  __syncthreads();
  if (tid < 16) {
    int t = w[tid];
#pragma unroll
    for (int off = 8; off >= 1; off >>= 1) t += __shfl_xor(t, off, 16);
    if (tid == 0) a.psum[ty][blockIdx.x] = t;
  }
}

__global__ __launch_bounds__(64) void scan_p2(CsrArgs a) {
  int ty = blockIdx.y;
  int nb = (a.N[ty] + 1023) / 1024;
  int tid = threadIdx.x;
  int v = (tid < nb) ? a.psum[ty][tid] : 0;
  int x = v;
#pragma unroll
  for (int off = 1; off < 64; off <<= 1) {
    int y = __shfl_up(x, off, 64);
    if (tid >= off) x += y;
  }
  if (tid < nb) a.psum[ty][tid] = x - v;  // exclusive
}

__global__ __launch_bounds__(1024) void scan_p3(CsrArgs a) {
  int ty = blockIdx.y;
  int n = a.N[ty];
  int base = blockIdx.x * 1024;
  if (base >= n) return;
  int tid = threadIdx.x, lane = tid & 63, wv = tid >> 6;
  int i = base + tid;
  int v = (i < n) ? a.cnt[ty][i] : 0;
  int x = v;
#pragma unroll
  for (int off = 1; off < 64; off <<= 1) {
    int y = __shfl_up(x, off, 64);
    if (lane >= off) x += y;
  }
  __shared__ int w[16];
  if (lane == 63) w[wv] = x;
  __syncthreads();
  if (tid < 16) {
    int t = w[tid];
#pragma unroll
    for (int off = 1; off < 16; off <<= 1) {
      int y = __shfl_up(t, off, 16);
      if (tid >= off) t += y;
    }
    w[tid] = t;
  }
  __syncthreads();
  int woff = (wv == 0) ? 0 : w[wv - 1];
  int incl = a.psum[ty][blockIdx.x] + woff + x;
  if (i < n) {
    a.rowptr[ty][i + 1] = incl;
    a.cnt[ty][i] = incl - v;  // cursor (exclusive)
  }
  if (i == 0) a.rowptr[ty][0] = 0;
}

// Fused scatter+gather: one pass over edges; reads dst/src/ea coalesced,
// writes srcC + eaC record at the cursor slot directly (no eidx indirection).
// eaC record: [e0,e1,e2,e3,e4, t0*inv, t1*inv, t2*inv] (temp pre-folded).
__global__ void scatter_b(CsrArgs a) {
  int ty = blockIdx.y;
  int i = blockIdx.x * 256 + threadIdx.x;
  if (i >= a.E[ty]) return;
  int p = atomicAdd(&a.cnt[ty][a.dst[ty][i]], 1);
  a.srcC[ty][p] = a.src[ty][i];
  const float* s = a.ea[ty] + (size_t)i * 6;
  float e3 = s[3];
  float inv = 1.f / fmaxf(e3, 1e-6f);
  float4 r0 = make_float4(s[0], s[1], s[2], e3);
  float4 r1 = make_float4(s[4], a.tmp0[ty] * inv, a.tmp1[ty] * inv,
                          a.tmp2[ty] * inv);
  float* d = a.eaC[ty] + (size_t)p * 8;
  *(float4*)d = r0;
  *(float4*)(d + 4) = r1;
}

// ---------------- merged projections: bus cast + gen 16->32 proj ----------
__global__ void proj_cast(const float* __restrict__ xb, const float* __restrict__ xg,
                          const float* __restrict__ w, const float* __restrict__ b,
                          u16* __restrict__ ob, u16* __restrict__ og, int nCast) {
  if ((int)blockIdx.x < nCast) {
    int i = blockIdx.x * 256 + threadIdx.x;
    if (i < NBUS * 32) ob[i] = f2b(xb[i]);
  } else {
    int idx = (blockIdx.x - nCast) * 256 + threadIdx.x;
    if (idx >= NGEN * 32) return;
    int i = idx >> 5, c = idx & 31;
    float acc = b[c];
#pragma unroll
    for (int k = 0; k < 16; ++k) acc += xg[i * 16 + k] * w[k * 32 + c];
    og[idx] = f2b(acc);
  }
}

struct PackArgs {
  const float* src[24];
  int off[24];
  int lgN[24];
  int total[24];
  int K[24];
};
__global__ void pack_multi(PackArgs a, u16* __restrict__ Wt) {
  int j = blockIdx.y;
  int idx = blockIdx.x * 256 + threadIdx.x;
  if (idx >= a.total[j]) return;
  int N1 = (1 << a.lgN[j]) - 1;
  int n = idx & N1;
  int k = idx >> a.lgN[j];
  Wt[(size_t)a.off[j] + (size_t)n * a.K[j] + k] = f2b(a.src[j][idx]);
}

// Merged bus+gen GEMM: global_load_lds w=16, XOR swizzle.
// Epilogue: C restaged through LDS -> 16B/lane coalesced bf16x8 stores.
__global__ __launch_bounds__(256) void gemm_both(
    const u16* __restrict__ Ab, const u16* __restrict__ Ag,
    const u16* __restrict__ Wt, int goff,
    u16* __restrict__ Cb, u16* __restrict__ Cg,
    int K, int Nb, int Ng, int ybus)
{
  __shared__ __align__(16) u16 As[128 * 32];
  __shared__ __align__(16) u16 Bs[128 * 32];
  __shared__ __align__(16) u16 Cs[32 * 128];
  const int t = threadIdx.x;
  const int w = t >> 6, lane = t & 63;
  const u16* A; const u16* W; u16* C; int M, Ncols, bn;
  if ((int)blockIdx.y < ybus) {
    A = Ab; W = Wt; C = Cb; M = NBUS; Ncols = Nb; bn = blockIdx.y * 128;
  } else {
    A = Ag; W = Wt + goff; C = Cg; M = NGEN; Ncols = Ng; bn = (blockIdx.y - ybus) * 128;
  }
  const int bm = blockIdx.x * 128;
  if (bm >= M) return;
  const int wm = (w & 1) * 64, wn = (w >> 1) * 64;
  const int lr = lane & 15, q = lane >> 4;
  const int srow = lane >> 2;
  const int blk = (lane & 3) ^ (srow & 3);
  f32x4 acc[4][4] = {};
  for (int k0 = 0; k0 < K; k0 += 32) {
#pragma unroll
    for (int sseg = 0; sseg < 2; ++sseg) {
      int seg = w + (sseg << 2);
      int row = (seg << 4) + srow;
      int ga = bm + row; if (ga > M - 1) ga = M - 1;
      const u16* gpa = A + (size_t)ga * K + k0 + (blk << 3);
      __builtin_amdgcn_global_load_lds((AS1 void*)gpa, (AS3 void*)(As + (seg << 9)),
                                       16, 0, 0);
      int gb = bn + row;
      const u16* gpb = W + (size_t)gb * K + k0 + (blk << 3);
      __builtin_amdgcn_global_load_lds((AS1 void*)gpb, (AS3 void*)(Bs + (seg << 9)),
                                       16, 0, 0);
    }
    __syncthreads();
    bf16x8 af[4], bg[4];
#pragma unroll
    for (int i = 0; i < 4; ++i) {
      int r = wm + i * 16 + lr;
      af[i] = *(const bf16x8*)&As[(r << 5) + ((q ^ (r & 3)) << 3)];
    }
#pragma unroll
    for (int j = 0; j < 4; ++j) {
      int r = wn + j * 16 + lr;
      bg[j] = *(const bf16x8*)&Bs[(r << 5) + ((q ^ (r & 3)) << 3)];
    }
#pragma unroll
    for (int i = 0; i < 4; ++i)
#pragma unroll
      for (int j = 0; j < 4; ++j)
        acc[i][j] = __builtin_amdgcn_mfma_f32_16x16x32_bf16(
            af[i], bg[j], acc[i][j], 0, 0, 0);
    __syncthreads();
  }
  // coalesced C-write: per i-block, stage 32x128 u16 in LDS, then 16B/lane
#pragma unroll
  for (int i = 0; i < 4; ++i) {
    __syncthreads();
    int lrow = (wm >> 2) + q * 4;   // wm=0 -> rows 0-15, wm=64 -> rows 16-31
#pragma unroll
    for (int j = 0; j < 4; ++j)
#pragma unroll
      for (int r = 0; r < 4; ++r)
        Cs[(lrow + r) * 128 + wn + j * 16 + lr] = f2b(acc[i][j][r]);
    __syncthreads();
#pragma unroll
    for (int it = 0; it < 2; ++it) {
      int chunk = t + it * 256;        // 512 chunks of 8 u16 (16B)
      int row = chunk >> 4;            // 0..31
      int cg = (chunk & 15) * 8;       // 0..120
      int grow = bm + ((row & 16) ? 64 : 0) + i * 16 + (row & 15);
      int gcol = bn + cg;
      if (grow < M && gcol < Ncols)
        *(bf16x8*)&C[(size_t)grow * Ncols + gcol] =
            *(const bf16x8*)&Cs[row * 128 + cg];
    }
  }
}

// ---------------- fused GATv2 conv ----------------
// R13 body exactly (depth-2 pair pipeline, DPP reduces everywhere, SGPR ea
// loads, 32-bit gather math, 44 VGPR). Block geometry: 128 threads = 2 waves
// = 2 nodes/block. Monotone law measured at constant VGPR44:
// 16w:76.7us / 8w:65.0 / 4w:56.3 -> block retire = max over waves (degree
// straggler) + N-contiguous-slot placement; both shrink with N.

#define CS_F1(lv, ev, fv, idx) do { \
    int rc_ = (idx) < nch ? (idx) : nch - 1; \
    int s_ = __builtin_amdgcn_readlane(vsrc, rc_); \
    lv = *(const ushort4*)(xl + (size_t)(unsigned)(s_ * ldl + ch)); \
    const float* ep_ = ebase + (unsigned)(rc_ * 8); \
    ev = *(const float4*)ep_; \
    fv = *(const float4*)(ep_ + 4); \
  } while (0)

#define CS_FETCH(S, base) do { \
    CS_F1(l##S##0, e##S##0, f##S##0, (base)); \
    CS_F1(l##S##1, e##S##1, f##S##1, (base) + 1); \
  } while (0)

#define CS_EDGE(xv, ev, fv, pv) do { \
    f32x4 m_ = xv + rx; \
    m_ = __builtin_elementwise_fma(splat4(ev.x), w0, m_); \
    m_ = __builtin_elementwise_fma(splat4(ev.y), w1, m_); \
    m_ = __builtin_elementwise_fma(splat4(ev.z), w2, m_); \
    m_ = __builtin_elementwise_fma(splat4(ev.w), w3, m_); \
    m_ = __builtin_elementwise_fma(splat4(fv.x), w4, m_); \
    float t_ = (TS == 1) ? fv.y : (TS == 2) ? fv.z : fv.w; \
    m_ = __builtin_elementwise_fma(splat4(t_), w5, m_); \
    m_ = __builtin_elementwise_max(m_, m_ * 0.2f); \
    pv = m_.x * av.x; \
    pv = fmaf(m_.y, av.y, pv); \
    pv = fmaf(m_.z, av.z, pv); \
    pv = fmaf(m_.w, av.w, pv); \
  } while (0)

#define CS_COMPUTE(S, base) do { \
    f32x4 x0_ = b2f4(l##S##0), x1_ = b2f4(l##S##1); \
    float p0_, p1_; \
    CS_EDGE(x0_, e##S##0, f##S##0, p0_); \
    CS_EDGE(x1_, e##S##1, f##S##1, p1_); \
    RED16(p0_); \
    RED16(p1_); \
    if ((base) >= nch) p0_ = -INFINITY; \
    if ((base) + 1 >= nch) p1_ = -INFINITY; \
    float nm_ = fmaxf(mx, fmaxf(p0_, p1_)); \
    float sc_ = __expf(mx - nm_); \
    float q0_ = __expf(p0_ - nm_), q1_ = __expf(p1_ - nm_); \
    mx = nm_; \
    den = den * sc_ + (q0_ + q1_); \
    acc = acc * splat4(sc_); \
    acc = __builtin_elementwise_fma(splat4(q0_), x0_, acc); \
    acc = __builtin_elementwise_fma(splat4(q1_), x1_, acc); \
  } while (0)

template<int TS>
__device__ __forceinline__ f32x4 conv_set(
    int node, int beg, int end, int ch,
    const int* __restrict__ srcc, const float* __restrict__ eac,
    const u16* __restrict__ xl, int ldl,
    const u16* __restrict__ xr, int ldr,
    const float* __restrict__ We, const float* __restrict__ att)
{
  f32x4 w0 = *(const f32x4*)(We + ch);
  f32x4 w1 = *(const f32x4*)(We + 256 + ch);
  f32x4 w2 = *(const f32x4*)(We + 512 + ch);
  f32x4 w3 = *(const f32x4*)(We + 768 + ch);
  f32x4 w4 = *(const f32x4*)(We + 1024 + ch);
  f32x4 w5 = *(const f32x4*)(We + 1280 + ch);
  f32x4 av = *(const f32x4*)(att + ch);
  f32x4 rx = b2f4(*(const ushort4*)(xr + (size_t)(unsigned)(node * ldr + ch)));
  float mx = -INFINITY, den = 0.f;
  f32x4 acc = {0.f, 0.f, 0.f, 0.f};
  int lane = ch >> 2;

  for (int cb = beg; cb < end; cb += 64) {
    int nch = end - cb;
    if (nch > 64) nch = 64;
    nch = __builtin_amdgcn_readfirstlane(nch);           // prove uniform
    int cbu = __builtin_amdgcn_readfirstlane(cb);        // prove uniform
    const float* ebase = eac + (size_t)(unsigned)cbu * 8u;
    int li = lane < nch ? lane : nch - 1;
    int vsrc = srcc[cb + li];   // one coalesced load covers 64 source indices
    int np = (nch + 1) >> 1;

    ushort4 la0, la1, lb0, lb1;
    float4 ea0, ea1, eb0, eb1;
    float4 fa0, fa1, fb0, fb1;

    CS_FETCH(a, 0);
    int g = 0;
    for (; g + 2 < np; g += 2) {
      CS_FETCH(b, (g + 1) << 1);
      CS_COMPUTE(a, g << 1);
      CS_FETCH(a, (g + 2) << 1);
      CS_COMPUTE(b, (g + 1) << 1);
    }
    if (g + 1 < np) {
      CS_FETCH(b, (g + 1) << 1);
      CS_COMPUTE(a, g << 1);
      CS_COMPUTE(b, (g + 1) << 1);
    } else {
      CS_COMPUTE(a, g << 1);
    }
  }
  float inv = 1.f / (den + 1e-16f);
  return acc * splat4(inv);
}

struct ConvP {
  const int* __restrict__ rpA; const int* __restrict__ srcA;
  const float* __restrict__ eaA;
  const u16* __restrict__ xlA; const u16* __restrict__ xrA;
  const float* __restrict__ WeA; const float* __restrict__ attA;
  const int* __restrict__ rpB; const int* __restrict__ srcB;
  const float* __restrict__ eaB;
  const u16* __restrict__ xlB; const u16* __restrict__ xrB;
  const float* __restrict__ WeB; const float* __restrict__ attB;
  const float* __restrict__ b1; const float* __restrict__ b2;
  const float* __restrict__ lnw; const float* __restrict__ lnb;
  const u16* __restrict__ res16;
  float* __restrict__ outf; u16* __restrict__ out16;
  int ldlA, ldrA, ldlB, ldrB, ld16, N;
};

// One launch per layer: blocks [0,nbBus) do bus nodes, [nbBus,..) gen nodes.
// 128 threads = 2 waves = 2 nodes per block.
// MODE 0: LN256 + bf16-residual + ELU, write bf16 state.
// MODE 1: head-mean + LN64 + bf16-residual, write d_out (fp32).
template<int MODE, int TS>
__global__ __launch_bounds__(128) void conv_fused(ConvP bus, ConvP gen, int nbBus) {
  const bool isb = (int)blockIdx.x < nbBus;
  const int grp = isb ? blockIdx.x : blockIdx.x - nbBus;
#define SEL(f) (isb ? bus.f : gen.f)
  const int* __restrict__ rpA = SEL(rpA);
  const int* __restrict__ srcA = SEL(srcA);
  const float* __restrict__ eaA = SEL(eaA);
  const u16* __restrict__ xlA = SEL(xlA);
  const u16* __restrict__ xrA = SEL(xrA);
  const float* __restrict__ WeA = SEL(WeA);
  const float* __restrict__ attA = SEL(attA);
  const int* __restrict__ rpB = SEL(rpB);
  const int N = SEL(N);
  const int ldlA = SEL(ldlA), ldrA = SEL(ldrA);

  int node = grp * 2 + (threadIdx.x >> 6);
  int lane = threadIdx.x & 63;
  if (node >= N) return;
  int ch = lane << 2;
  int begA = rpA[node], endA = rpA[node + 1];
  int begB = 0, endB = 0;
  if (rpB) { begB = rpB[node]; endB = rpB[node + 1]; }  // overlap rp chains
  f32x4 o = conv_set<TS>(node, begA, endA, ch, srcA, eaA, xlA, ldlA,
                         xrA, ldrA, WeA, attA);
  if (rpB && begB < endB) {  // uniform branch; gen side has rpB==null
    f32x4 ob = conv_set<TS>(node, begB, endB, ch, SEL(srcB), SEL(eaB),
                            SEL(xlB), SEL(ldlB), SEL(xrB), SEL(ldrB),
                            SEL(WeB), SEL(attB));
    o[0] += ob[0]; o[1] += ob[1]; o[2] += ob[2]; o[3] += ob[3];
  }
  const float* __restrict__ b1 = SEL(b1);
  const float* __restrict__ b2 = SEL(b2);
  const float* __restrict__ lnw = SEL(lnw);
  const float* __restrict__ lnb = SEL(lnb);
  const u16* __restrict__ res16 = SEL(res16);
  const int ld16 = SEL(ld16);
  if (MODE == 0) {
    int c = ch;
    float4 bb = *(const float4*)(b1 + c);
    float v0 = o[0] + bb.x, v1 = o[1] + bb.y, v2 = o[2] + bb.z, v3 = o[3] + bb.w;
    if (b2) {
      float4 b2v = *(const float4*)(b2 + c);
      v0 += b2v.x; v1 += b2v.y; v2 += b2v.z; v3 += b2v.w;
    }
    // LN256 reduces: DPP within 16 lanes, shfl for xor16/xor32 only
    float s = v0 + v1 + v2 + v3;
    RED16(s);
    s += __shfl_xor(s, 16); s += __shfl_xor(s, 32);
    float mu = s * (1.f / 256.f);
    float d0 = v0 - mu, d1 = v1 - mu, d2 = v2 - mu, d3 = v3 - mu;
    float q = d0*d0 + d1*d1 + d2*d2 + d3*d3;
    RED16(q);
    q += __shfl_xor(q, 16); q += __shfl_xor(q, 32);
    float rs = rsqrtf(q * (1.f / 256.f) + 1e-5f);
    float4 lw = *(const float4*)(lnw + c);
    float4 lb = *(const float4*)(lnb + c);
    float y0 = d0 * rs * lw.x + lb.x;
    float y1 = d1 * rs * lw.y + lb.y;
    float y2 = d2 * rs * lw.z + lb.z;
    float y3 = d3 * rs * lw.w + lb.w;
    ushort4 r = *(const ushort4*)(res16 + (size_t)node * ld16 + c);
    y0 += b2f(r.x); y1 += b2f(r.y); y2 += b2f(r.z); y3 += b2f(r.w);
    // ELU via HW v_exp (expm1f is a slow libm polynomial); tol 0.0625 >> err
    y0 = (y0 > 0.f) ? y0 : __expf(y0) - 1.f;
    y1 = (y1 > 0.f) ? y1 : __expf(y1) - 1.f;
    y2 = (y2 > 0.f) ? y2 : __expf(y2) - 1.f;
    y3 = (y3 > 0.f) ? y3 : __expf(y3) - 1.f;
    ushort4 o16;
    o16.x = f2b(y0); o16.y = f2b(y1); o16.z = f2b(y2); o16.w = f2b(y3);
    u16* __restrict__ out16 = SEL(out16);
    *(ushort4*)(out16 + (size_t)node * 256 + c) = o16;
  } else {
    // head mean: sum over the 4 head groups (lanes xor 16, 32)
    float h0 = o[0], h1 = o[1], h2 = o[2], h3 = o[3];
    h0 += __shfl_xor(h0, 16); h0 += __shfl_xor(h0, 32);
    h1 += __shfl_xor(h1, 16); h1 += __shfl_xor(h1, 32);
    h2 += __shfl_xor(h2, 16); h2 += __shfl_xor(h2, 32);
    h3 += __shfl_xor(h3, 16); h3 += __shfl_xor(h3, 32);
    int cc = (lane & 15) << 2;
    float4 bb = *(const float4*)(b1 + cc);
    float v0 = 0.25f * h0 + bb.x, v1 = 0.25f * h1 + bb.y;
    float v2 = 0.25f * h2 + bb.z, v3 = 0.25f * h3 + bb.w;
    if (b2) {
      float4 b2v = *(const float4*)(b2 + cc);
      v0 += b2v.x; v1 += b2v.y; v2 += b2v.z; v3 += b2v.w;
    }
    // LN64 reduces are exact 16-lane sums -> pure DPP
    float s = v0 + v1 + v2 + v3;
    RED16(s);
    float mu = s * (1.f / 64.f);
    float d0 = v0 - mu, d1 = v1 - mu, d2 = v2 - mu, d3 = v3 - mu;
    float q = d0*d0 + d1*d1 + d2*d2 + d3*d3;
    RED16(q);
    float rs = rsqrtf(q * (1.f / 64.f) + 1e-5f);
    float4 lw = *(const float4*)(lnw + cc);
    float4 lb = *(const float4*)(lnb + cc);
    ushort4 r = *(const ushort4*)(res16 + (size_t)node * ld16 + cc);
    float y0 = d0 * rs * lw.x + lb.x + b2f(r.x);
    float y1 = d1 * rs * lw.y + lb.y + b2f(r.y);
    float y2 = d2 * rs * lw.z + lb.z + b2f(r.z);
    float y3 = d3 * rs * lw.w + lb.w + b2f(r.w);
    float* __restrict__ outf = SEL(outf);
    if (lane < 16)
      *(float4*)(outf + (size_t)node * 64 + cc) = make_float4(y0, y1, y2, y3);
  }
#undef SEL
}

extern "C" void kernel_launch(void* const* d_in, const int* in_sizes, int n_in,
                              void* d_out, int out_size, void* d_ws, size_t ws_size,
                              hipStream_t stream) {
  const float* x_bus = (const float*)d_in[0];
  const float* x_gen = (const float*)d_in[1];
  const float* ea[3] = {(const float*)d_in[2], (const float*)d_in[3], (const float*)d_in[4]};
  const float* pw = (const float*)d_in[5];
  const float* pb = (const float*)d_in[6];
  const float* Wl[3] = {(const float*)d_in[7], (const float*)d_in[15], (const float*)d_in[23]};
  const float* Wr[3] = {(const float*)d_in[8], (const float*)d_in[16], (const float*)d_in[24]};
  const float* We[3] = {(const float*)d_in[9], (const float*)d_in[17], (const float*)d_in[25]};
  const float* att[3] = {(const float*)d_in[10], (const float*)d_in[18], (const float*)d_in[26]};
  const float* bc[3] = {(const float*)d_in[11], (const float*)d_in[19], (const float*)d_in[27]};
  const float* temp[3] = {(const float*)d_in[12], (const float*)d_in[20], (const float*)d_in[28]};
  const float* lnw[3] = {(const float*)d_in[13], (const float*)d_in[21], (const float*)d_in[29]};
  const float* lnb[3] = {(const float*)d_in[14], (const float*)d_in[22], (const float*)d_in[30]};
  const float* rp0_w = (const float*)d_in[31];
  const float* rp2_w = (const float*)d_in[33];
  const int* srcs[3] = {(const int*)d_in[35], (const int*)d_in[37], (const int*)d_in[39]};
  const int* dsts[3] = {(const int*)d_in[36], (const int*)d_in[38], (const int*)d_in[40]};

  float* ws = (float*)d_ws;
  size_t off = 0;
  auto alloc = [&](size_t n) { float* p = ws + off; off += n; return p; };
  u16* xb16_0 = (u16*)alloc((size_t)NBUS * 16);
  u16* xg16_0 = (u16*)alloc((size_t)NGEN * 16);
  u16* xb16 = (u16*)alloc((size_t)NBUS * 128);
  u16* xg16 = (u16*)alloc((size_t)NGEN * 128);
  u16* Pbus = (u16*)alloc((size_t)NBUS * 640);
  u16* Pgen = (u16*)alloc((size_t)NGEN * 384);
  u16* Wt = (u16*)alloc((size_t)886000 / 2);  // 884736 packed elements + pad
  float* eaC0 = alloc((size_t)NEL * 8);
  float* eaC1 = alloc((size_t)NEG * 8);
  float* eaC2 = alloc((size_t)NEG * 8);
  int* cw_all = (int*)alloc(NBUS + NBUS + NGEN);  // 3 histograms, contiguous
  int* rp_line = (int*)alloc(NBUS + 1);
  int* rp_g2b = (int*)alloc(NBUS + 1);
  int* rp_b2g = (int*)alloc(NGEN + 1);
  int* sc_line = (int*)alloc(NEL);
  int* sc_g2b = (int*)alloc(NEG);
  int* sc_b2g = (int*)alloc(NEG);
  int* psum = (int*)alloc(3 * 32);
  (void)ws_size; (void)in_sizes; (void)n_in; (void)out_size;

  CsrArgs ca;
  for (int t = 0; t < 3; ++t) { ca.dst[t] = dsts[t]; ca.src[t] = srcs[t]; ca.ea[t] = ea[t]; }
  ca.tmp0 = temp[0]; ca.tmp1 = temp[1]; ca.tmp2 = temp[2];
  ca.cnt[0] = cw_all; ca.cnt[1] = cw_all + NBUS; ca.cnt[2] = cw_all + 2 * NBUS;
  ca.rowptr[0] = rp_line; ca.rowptr[1] = rp_g2b; ca.rowptr[2] = rp_b2g;
  ca.srcC[0] = sc_line; ca.srcC[1] = sc_g2b; ca.srcC[2] = sc_b2g;
  ca.eaC[0] = eaC0; ca.eaC[1] = eaC1; ca.eaC[2] = eaC2;
  ca.psum[0] = psum; ca.psum[1] = psum + 32; ca.psum[2] = psum + 64;
  ca.E[0] = NEL; ca.E[1] = NEG; ca.E[2] = NEG;
  ca.N[0] = NBUS; ca.N[1] = NBUS; ca.N[2] = NGEN;

  int egrid = (NEL + 255) / 256;
  hipLaunchKernelGGL(zeroi, dim3(64), dim3(1024), 0, stream, cw_all, 2 * NBUS + NGEN);
  hipLaunchKernelGGL(hist_b, dim3(egrid, 3), dim3(256), 0, stream, ca);
  hipLaunchKernelGGL(scan_p1, dim3(30, 3), dim3(1024), 0, stream, ca);
  hipLaunchKernelGGL(scan_p2, dim3(1, 3), dim3(64), 0, stream, ca);
  hipLaunchKernelGGL(scan_p3, dim3(30, 3), dim3(1024), 0, stream, ca);
  hipLaunchKernelGGL(scatter_b, dim3(egrid, 3), dim3(256), 0, stream, ca);

  // merged bus-cast + gen-proj
  const int nCast = (NBUS * 32 + 255) / 256;              // 3750
  const int nProj = (NGEN * 32 + 255) / 256;              // 750
  hipLaunchKernelGGL(proj_cast, dim3(nCast + nProj), dim3(256), 0, stream,
                     x_bus, x_gen, pw, pb, xb16_0, xg16_0, nCast);

  // ---- single upfront pack of all 3 layers (+ residual projections) ----
  const int K_l[3] = {32, 256, 256};
  const int Nbus_l[3] = {1280, 1024, 1088};
  const int Ngen_l[3] = {768, 512, 576};
  int Lbase[3], goff_l[3];
  {
    int b = 0;
    for (int l = 0; l < 3; ++l) {
      Lbase[l] = b;
      goff_l[l] = Nbus_l[l] * K_l[l];
      b += (Nbus_l[l] + Ngen_l[l]) * K_l[l];
    }
  }
  PackArgs pa = {};
  int ns = 0;
  auto add = [&](const float* src, int offel, int N_, int lg, int K) {
    pa.src[ns] = src; pa.off[ns] = offel; pa.lgN[ns] = lg;
    pa.total[ns] = K * N_; pa.K[ns] = K; ++ns;
  };
  for (int l = 0; l < 3; ++l) {
    int K = K_l[l];
    size_t sl = (size_t)K * 256;
    int L = Lbase[l], go = goff_l[l];
    add(Wl[l], L, 256, 8, K);
    add(Wr[l], L + 256 * K, 256, 8, K);
    add(Wr[l] + sl, L + 512 * K, 256, 8, K);
    add(Wl[l] + 2 * sl, L + 768 * K, 256, 8, K);
    add(Wl[l] + sl, L + go, 256, 8, K);
    add(Wr[l] + 2 * sl, L + go + 256 * K, 256, 8, K);
    if (l == 0) {
      add(rp0_w, L + 1024 * K, 256, 8, K);
      add(rp0_w + 32 * 256, L + go + 512 * K, 256, 8, K);
    } else if (l == 2) {
      add(rp2_w, L + 1024 * K, 64, 6, K);
      add(rp2_w + 256 * 64, L + go + 512 * K, 64, 6, K);
    }
  }
  hipLaunchKernelGGL(pack_multi, dim3(256, ns), dim3(256), 0, stream, pa, Wt);

  const int nbBus = (NBUS + 1) / 2;   // 15000
  const int nbGen = (NGEN + 1) / 2;   // 3000

  for (int l = 0; l < 3; ++l) {
    const int K = K_l[l];
    const int Nb = Nbus_l[l], Ng = Ngen_l[l];
    const u16* Ab = (l == 0) ? xb16_0 : xb16;
    const u16* Ag = (l == 0) ? xg16_0 : xg16;

    // --- merged bus+gen projection GEMM ---
    int ybus = (Nb + 127) / 128, ygen = (Ng + 127) / 128;
    hipLaunchKernelGGL(gemm_both, dim3((NBUS + 127) / 128, ybus + ygen),
                       dim3(256), 0, stream,
                       Ab, Ag, Wt + Lbase[l], goff_l[l], Pbus, Pgen, K, Nb, Ng, ybus);

    // --- fused conv + LN/residual/activation (one launch: bus + gen) ---
    ConvP pb_ = {};
    pb_.rpA = rp_line; pb_.srcA = sc_line; pb_.eaA = eaC0;
    pb_.xlA = Pbus; pb_.ldlA = Nb; pb_.xrA = Pbus + 256; pb_.ldrA = Nb;
    pb_.WeA = We[l]; pb_.attA = att[l];
    pb_.rpB = rp_g2b; pb_.srcB = sc_g2b; pb_.eaB = eaC1;
    pb_.xlB = Pgen; pb_.ldlB = Ng; pb_.xrB = Pbus + 512; pb_.ldrB = Nb;
    pb_.WeB = We[l] + 1536; pb_.attB = att[l] + 256;
    pb_.N = NBUS;
    ConvP pg_ = {};
    pg_.rpA = rp_b2g; pg_.srcA = sc_b2g; pg_.eaA = eaC2;
    pg_.xlA = Pbus + 768; pg_.ldlA = Nb; pg_.xrA = Pgen + 256; pg_.ldrA = Ng;
    pg_.WeA = We[l] + 3072; pg_.attA = att[l] + 512;
    pg_.rpB = nullptr;
    pg_.N = NGEN;
    dim3 gall(nbBus + nbGen), blk(128);

    if (l < 2) {
      pb_.b1 = bc[l]; pb_.b2 = bc[l] + 256; pb_.lnw = lnw[l]; pb_.lnb = lnb[l];
      pg_.b1 = bc[l] + 512; pg_.b2 = nullptr;
      pg_.lnw = lnw[l] + 256; pg_.lnb = lnb[l] + 256;
      if (l == 0) {
        pb_.res16 = Pbus + 1024; pb_.ld16 = Nb;
        pg_.res16 = Pgen + 512; pg_.ld16 = Ng;
      } else {
        pb_.res16 = xb16; pb_.ld16 = 256;   // read-before-write per node: safe
        pg_.res16 = xg16; pg_.ld16 = 256;
      }
      pb_.outf = nullptr; pb_.out16 = xb16;
      pg_.outf = nullptr; pg_.out16 = xg16;
      if (l == 0)
        hipLaunchKernelGGL((conv_fused<0, 1>), gall, blk, 0, stream, pb_, pg_, nbBus);
      else
        hipLaunchKernelGGL((conv_fused<0, 2>), gall, blk, 0, stream, pb_, pg_, nbBus);
    } else {
      pb_.b1 = bc[2]; pb_.b2 = bc[2] + 64; pb_.lnw = lnw[2]; pb_.lnb = lnb[2];
      pb_.res16 = Pbus + 1024; pb_.ld16 = Nb;
      pb_.outf = (float*)d_out; pb_.out16 = nullptr;
      pg_.b1 = bc[2] + 128; pg_.b2 = nullptr; pg_.lnw = lnw[2] + 64; pg_.lnb = lnb[2] + 64;
      pg_.res16 = Pgen + 512; pg_.ld16 = Ng;
      pg_.outf = (float*)d_out + (size_t)NBUS * 64; pg_.out16 = nullptr;
      hipLaunchKernelGGL((conv_fused<1, 3>), gall, blk, 0, stream, pb_, pg_, nbBus);
    }
  }
}